// Round 2
// baseline (72.290 us; speedup 1.0000x reference)
//
#include <hip/hip_runtime.h>

#define HH 352
#define WW 1216
#define NBOX 16
#define KCAND 61
#define HN 88    // H/4
#define WN 304   // W/4
#define THREADS 1024
#define NWAVE (THREADS / 64)

// One block per box: accumulate all 61 candidate losses over the box region,
// block-reduce, wave-argmin (first-index tie-break), write output directly.
// Single launch, no workspace, no atomics -> deterministic.
__global__ __launch_bounds__(THREADS) void refine_kernel(
    const float* __restrict__ nocs,    // (3, HN, WN)
    const float* __restrict__ dd,      // (HH, WW, 3)
    const int*   __restrict__ boxes,   // (N, 4)
    const float* __restrict__ pc,      // (N, 2)
    const float* __restrict__ bdepth,  // (N,)
    const float* __restrict__ dims,    // (N, 3)
    const float* __restrict__ intr,    // (3, 3)
    float* __restrict__ out)           // (N, 3)
{
    const int box = blockIdx.x;
    const int tid = threadIdx.x;

    const int x1 = boxes[box*4+0], y1 = boxes[box*4+1];
    const int x2 = boxes[box*4+2], y2 = boxes[box*4+3];
    const int bw = x2 - x1;
    const int npix = bw * (y2 - y1);

    const float fx = intr[0], cx = intr[2], fy = intr[4], cy = intr[5];
    const float ax = (pc[box*2+0] - cx) / fx;
    const float ay = (pc[box*2+1] - cy) / fy;
    const float d_start = bdepth[box] - 3.0f;   // k=0 candidate depth
    const float dax = 0.1f * ax;
    const float day = 0.1f * ay;

    // magic-multiply for p / bw (bw >= 1; exact for p < 2^24 here)
    const unsigned magic = (bw > 1) ? (0xFFFFFFFFu / (unsigned)bw + 1u) : 0u;

    float acc[KCAND];
#pragma unroll
    for (int k = 0; k < KCAND; ++k) acc[k] = 0.f;

    for (int p = tid; p < npix; p += THREADS) {
        unsigned q = (bw > 1) ? __umulhi((unsigned)p, magic) : (unsigned)p;
        const int r   = p - (int)q * bw;
        const int row = y1 + (int)q;
        const int x   = x1 + r;

        const float* dp = dd + ((size_t)row * WW + x) * 3;
        const float dz = dp[2];
        if (dz < 1.0f) continue;   // empty mask

        // bilinear 4x upsample coords (half-pixel, clamp-to-edge)
        const int ry  = row & 3;
        const int ym  = row >> 2;
        const int yy0 = ym + ((ry >= 2) ? 0 : -1);
        const float wy = 0.125f + 0.25f * (float)((ry + 2) & 3);
        const int ya = max(yy0, 0);
        const int yb = min(yy0 + 1, HN - 1);

        const int rx  = x & 3;
        const int xm  = x >> 2;
        const int xx0 = xm + ((rx >= 2) ? 0 : -1);
        const float wx = 0.125f + 0.25f * (float)((rx + 2) & 3);
        const int xa = max(xx0, 0);
        const int xb = min(xx0 + 1, WN - 1);

        float b[3];
#pragma unroll
        for (int c = 0; c < 3; ++c) {
            const float* np_ = nocs + c * (HN * WN);
            const float v00 = np_[ya*WN + xa], v01 = np_[ya*WN + xb];
            const float v10 = np_[yb*WN + xa], v11 = np_[yb*WN + xb];
            const float v0 = v00 + (v01 - v00) * wx;
            const float v1 = v10 + (v11 - v10) * wy * 0.f + (v11 - v10) * wx; // placeholder avoided below
            (void)v1;
            const float v0_ = v00 + (v01 - v00) * wx;
            const float v1_ = v10 + (v11 - v10) * wx;
            const float nup = v0_ + (v1_ - v0_) * wy;
            b[c] = nup - dp[c];
            (void)v0;
        }

        // incremental candidate sweep: t_k+1 = t_k + step (no hoisted tables)
        float t0 = fmaf(ax, d_start, b[0]);
        float t1 = fmaf(ay, d_start, b[1]);
        float t2 = b[2] + d_start;
#pragma unroll
        for (int k = 0; k < KCAND; ++k) {
            acc[k] += fabsf(t0) + fabsf(t1) + fabsf(t2);
            t0 += dax;
            t1 += day;
            t2 += 0.1f;
        }
    }

    // block reduce: per-wave shuffle, lane0 -> LDS, then cross-wave sum
    const int lane = tid & 63;
    const int wave = tid >> 6;
    __shared__ float wbuf[NWAVE][KCAND];
#pragma unroll
    for (int k = 0; k < KCAND; ++k) {
        float v = acc[k];
        for (int off = 32; off; off >>= 1) v += __shfl_xor(v, off, 64);
        if (lane == 0) wbuf[wave][k] = v;
    }
    __syncthreads();

    if (tid < 64) {
        float loss = INFINITY;
        int kk = tid;
        if (tid < KCAND) {
            float s = 0.f;
#pragma unroll
            for (int w = 0; w < NWAVE; ++w) s += wbuf[w][tid];
            loss = s;
        }
        // wave argmin, ties -> smaller k (matches jnp.argmin)
        for (int off = 1; off < 64; off <<= 1) {
            const float ol = __shfl_xor(loss, off, 64);
            const int   ok = __shfl_xor(kk,   off, 64);
            if (ol < loss || (ol == loss && ok < kk)) { loss = ol; kk = ok; }
        }
        if (lane == 0) {
            const float dk = (d_start + 3.0f) + (0.1f * (float)kk - 3.0f);
            out[box*3+0] = ax * dk;
            out[box*3+1] = ay * dk + dims[box*3+1] * 0.5f;
            out[box*3+2] = dk;
        }
    }
}

extern "C" void kernel_launch(void* const* d_in, const int* in_sizes, int n_in,
                              void* d_out, int out_size, void* d_ws, size_t ws_size,
                              hipStream_t stream) {
    const float* nocs  = (const float*)d_in[0];
    const float* dd    = (const float*)d_in[1];
    const int*   boxes = (const int*)d_in[2];
    const float* pc    = (const float*)d_in[3];
    const float* bd    = (const float*)d_in[4];
    const float* dims  = (const float*)d_in[5];
    const float* intr  = (const float*)d_in[6];
    float* out = (float*)d_out;

    refine_kernel<<<NBOX, THREADS, 0, stream>>>(
        nocs, dd, boxes, pc, bd, dims, intr, out);
}

// Round 3
// 29.949 us; speedup vs baseline: 2.4138x; 2.4138x over previous
//
#include <hip/hip_runtime.h>

#define HH 352
#define WW 1216
#define NBOX 16
#define KCAND 61
#define HN 88    // H/4
#define WN 304   // W/4

#define SLICES 32
#define KGROUPS 4
#define KLEN 16          // ceil(61/4)
#define THREADS 256
#define NWAVE (THREADS / 64)

// Kernel 1: block = (slice, box, kgroup). Each thread accumulates KLEN
// candidate losses over a strided subset of the box's pixels, block-reduces,
// and writes partial[box][slice][k]. Deterministic (no atomics).
__global__ __launch_bounds__(THREADS) void loss_partial_kernel(
    const float* __restrict__ nocs,    // (3, HN, WN)
    const float* __restrict__ dd,      // (HH, WW, 3)
    const int*   __restrict__ boxes,   // (N, 4)
    const float* __restrict__ pc,      // (N, 2)
    const float* __restrict__ bdepth,  // (N,)
    const float* __restrict__ intr,    // (3, 3)
    float* __restrict__ partial,       // (N, S, K)
    int S)
{
    const int slice = blockIdx.x;
    const int box   = blockIdx.y;
    const int kg    = blockIdx.z;
    const int tid   = threadIdx.x;
    const int kbase = kg * KLEN;

    const int x1 = boxes[box*4+0], y1 = boxes[box*4+1];
    const int x2 = boxes[box*4+2], y2 = boxes[box*4+3];
    const int bw = x2 - x1;
    const int npix = bw * (y2 - y1);

    const float fx = intr[0], cx = intr[2], fy = intr[4], cy = intr[5];
    const float ax = (pc[box*2+0] - cx) / fx;
    const float ay = (pc[box*2+1] - cy) / fy;
    const float d0 = bdepth[box] + (0.1f * (float)kbase - 3.0f); // first k of group
    const float dax = 0.1f * ax;
    const float day = 0.1f * ay;

    // exact magic-multiply division p/bw (p < 2^15, bw <= 200)
    const unsigned magic = (bw > 1) ? (0xFFFFFFFFu / (unsigned)bw + 1u) : 0u;

    float acc[KLEN];
#pragma unroll
    for (int k = 0; k < KLEN; ++k) acc[k] = 0.f;

    const int stride = S * THREADS;
    for (int p = slice * THREADS + tid; p < npix; p += stride) {
        unsigned q = (bw > 1) ? __umulhi((unsigned)p, magic) : (unsigned)p;
        const int r   = p - (int)q * bw;
        const int row = y1 + (int)q;
        const int x   = x1 + r;

        const float* dp = dd + ((size_t)row * WW + x) * 3;
        const float dz = dp[2];
        if (dz < 1.0f) continue;   // empty mask

        // bilinear 4x upsample (half-pixel, clamp-to-edge)
        const int ry  = row & 3;
        const int yy0 = (row >> 2) + ((ry >= 2) ? 0 : -1);
        const float wy = 0.125f + 0.25f * (float)((ry + 2) & 3);
        const int ya = max(yy0, 0);
        const int yb = min(yy0 + 1, HN - 1);

        const int rx  = x & 3;
        const int xx0 = (x >> 2) + ((rx >= 2) ? 0 : -1);
        const float wx = 0.125f + 0.25f * (float)((rx + 2) & 3);
        const int xa = max(xx0, 0);
        const int xb = min(xx0 + 1, WN - 1);

        float b[3];
#pragma unroll
        for (int c = 0; c < 3; ++c) {
            const float* np_ = nocs + c * (HN * WN);
            const float v00 = np_[ya*WN + xa], v01 = np_[ya*WN + xb];
            const float v10 = np_[yb*WN + xa], v11 = np_[yb*WN + xb];
            const float v0 = v00 + (v01 - v00) * wx;
            const float v1 = v10 + (v11 - v10) * wx;
            b[c] = (v0 + (v1 - v0) * wy) - dp[c];
        }

        // incremental sweep over this block's KLEN candidates
        float t0 = fmaf(ax, d0, b[0]);
        float t1 = fmaf(ay, d0, b[1]);
        float t2 = b[2] + d0;
#pragma unroll
        for (int k = 0; k < KLEN; ++k) {
            acc[k] += fabsf(t0) + fabsf(t1) + fabsf(t2);
            t0 += dax;
            t1 += day;
            t2 += 0.1f;
        }
    }

    // block reduce: per-wave shuffle, lane0 -> LDS, then cross-wave sum
    const int lane = tid & 63;
    const int wave = tid >> 6;
    __shared__ float wbuf[NWAVE][KLEN];
#pragma unroll
    for (int k = 0; k < KLEN; ++k) {
        float v = acc[k];
        for (int off = 32; off; off >>= 1) v += __shfl_xor(v, off, 64);
        if (lane == 0) wbuf[wave][k] = v;
    }
    __syncthreads();
    if (tid < KLEN && kbase + tid < KCAND) {
        float s = 0.f;
#pragma unroll
        for (int w = 0; w < NWAVE; ++w) s += wbuf[w][tid];
        partial[((size_t)box * S + slice) * KCAND + (kbase + tid)] = s;
    }
}

// Kernel 2: per-box slice-sum + wave argmin (first-index tie-break) + output.
__global__ __launch_bounds__(64) void finalize_kernel(
    const float* __restrict__ partial,  // (N, S, K)
    const float* __restrict__ pc,
    const float* __restrict__ bdepth,
    const float* __restrict__ dims,     // (N,3)
    const float* __restrict__ intr,
    float* __restrict__ out,            // (N,3)
    int S)
{
    const int box  = blockIdx.x;
    const int lane = threadIdx.x;

    float loss = INFINITY;
    int kk = lane;
    if (lane < KCAND) {
        float s = 0.f;
        for (int sl = 0; sl < S; ++sl)
            s += partial[((size_t)box * S + sl) * KCAND + lane];
        loss = s;
    }
    for (int off = 1; off < 64; off <<= 1) {
        const float ol = __shfl_xor(loss, off, 64);
        const int   ok = __shfl_xor(kk,   off, 64);
        if (ol < loss || (ol == loss && ok < kk)) { loss = ol; kk = ok; }
    }
    if (lane == 0) {
        const float fx = intr[0], cx = intr[2], fy = intr[4], cy = intr[5];
        const float dk = bdepth[box] + (0.1f * (float)kk - 3.0f);
        const float axv = (pc[box*2+0] - cx) / fx;
        const float ayv = (pc[box*2+1] - cy) / fy;
        out[box*3+0] = axv * dk;
        out[box*3+1] = ayv * dk + dims[box*3+1] * 0.5f;
        out[box*3+2] = dk;
    }
}

extern "C" void kernel_launch(void* const* d_in, const int* in_sizes, int n_in,
                              void* d_out, int out_size, void* d_ws, size_t ws_size,
                              hipStream_t stream) {
    const float* nocs  = (const float*)d_in[0];
    const float* dd    = (const float*)d_in[1];
    const int*   boxes = (const int*)d_in[2];
    const float* pc    = (const float*)d_in[3];
    const float* bd    = (const float*)d_in[4];
    const float* dims  = (const float*)d_in[5];
    const float* intr  = (const float*)d_in[6];
    float* out     = (float*)d_out;
    float* partial = (float*)d_ws;

    int S = SLICES;
    while (S > 1 && (size_t)NBOX * S * KCAND * sizeof(float) > ws_size) S >>= 1;

    loss_partial_kernel<<<dim3(S, NBOX, KGROUPS), THREADS, 0, stream>>>(
        nocs, dd, boxes, pc, bd, intr, partial, S);
    finalize_kernel<<<NBOX, 64, 0, stream>>>(
        partial, pc, bd, dims, intr, out, S);
}